// Round 2
// baseline (365.258 us; speedup 1.0000x reference)
//
#include <hip/hip_runtime.h>
#include <hip/hip_bf16.h>

#define BATCH 65536
#define DDIM  256
#define HDIM  512
#define DT_C  0.1f
#define HDT_C 0.05f

typedef __attribute__((ext_vector_type(8))) __bf16 bf16x8;
typedef __attribute__((ext_vector_type(4))) float  f32x4;

__device__ __forceinline__ unsigned short bf16b(float f) {
  __bf16 h = (__bf16)f;
  return __builtin_bit_cast(unsigned short, h);
}
__device__ __forceinline__ float bf16f(unsigned short u) {
  unsigned int b = ((unsigned int)u) << 16;
  return __builtin_bit_cast(float, b);
}
__device__ __forceinline__ float tanh_fast(float x) {
  // tanh(x) = 1 - 2/(e^{2x}+1); stable at both tails (inf -> 1, 0 -> -1)
  float e = __expf(2.0f * x);
  return 1.0f - 2.0f * __builtin_amdgcn_rcpf(e + 1.0f);
}

// ---------------------------------------------------------------------------
// Fragment k-slot mapping (mu): element j of lane l covers k = kt*32 + (l>>4)*8 + j.
// Used consistently for A and B operands everywhere, so even if the HW k-order
// differs by a permutation the MFMA dot-product is unchanged.
// U_pk layout: [nt(32)][kt(8)][lane(64)][j(8)]  (n = nt*16 + (l&15), k over D=256)
// W_pk layout: [kt(16)][nt(16)][lane(64)][j(8)] (n = nt*16 + (l&15), k over H=512)
// Both give contiguous 32 KB chunks per 64-wide H-column chunk.
// ---------------------------------------------------------------------------
__global__ __launch_bounds__(256) void pack_uw(
    const float* __restrict__ U, const float* __restrict__ W,
    unsigned short* __restrict__ Upk, unsigned short* __restrict__ Wpk) {
  int t = blockIdx.x * 256 + threadIdx.x;   // 32768 threads, 16B out each
  int lane = t & 63;
  int g = lane >> 4, cl = lane & 15;
  alignas(16) unsigned short o[8];
  if (t < 16384) {
    int ktnt = t >> 6;
    int kt = ktnt & 7, nt = ktnt >> 3;
    int k0 = kt * 32 + g * 8, n = nt * 16 + cl;
#pragma unroll
    for (int j = 0; j < 8; ++j) o[j] = bf16b(U[(size_t)(k0 + j) * HDIM + n]);
    *reinterpret_cast<uint4*>(Upk + (size_t)t * 8) =
        *reinterpret_cast<const uint4*>(o);
  } else {
    int s = t - 16384;
    int ktnt = s >> 6;
    int nt = ktnt & 15, kt = ktnt >> 4;
    int k0 = kt * 32 + g * 8, n = nt * 16 + cl;
#pragma unroll
    for (int j = 0; j < 8; ++j) o[j] = bf16b(W[(size_t)(k0 + j) * DDIM + n]);
    *reinterpret_cast<uint4*>(Wpk + (size_t)s * 8) =
        *reinterpret_cast<const uint4*>(o);
  }
}

// Cooperative 32 KB global->LDS stage (256 threads, 16 B/lane, 8 iters).
// LDS dest is wave-uniform base; HW scatters lane i at base + i*16.
__device__ __forceinline__ void stage32k(const unsigned short* __restrict__ src,
                                         unsigned short* dst, int tid) {
  const char* s = reinterpret_cast<const char*>(src);
  char* d = reinterpret_cast<char*>(dst);
  int w = tid >> 6, lane = tid & 63;
#pragma unroll
  for (int i = 0; i < 8; ++i) {
    int o = i * 4096 + w * 1024;
    __builtin_amdgcn_global_load_lds(
        (const __attribute__((address_space(1))) void*)(s + o + lane * 16),
        (__attribute__((address_space(3))) void*)(d + o), 16, 0, 0);
  }
}

// One christoffel matmul chain: gacc[nt][r] = (tanh(A @ U) @ W) for this
// wave's 16 rows, A given as MFMA fragments xf[8]. C-layout output:
// element (nt, r) of lane l = G[row 4*(l>>4)+r][col nt*16 + (l&15)].
__device__ __forceinline__ void gemm_chain(
    const bf16x8 xf[8], f32x4 gacc[16],
    const unsigned short* __restrict__ Upk,
    const unsigned short* __restrict__ Wpk,
    unsigned short* stage, unsigned short* hxw, int tid, int lane) {
  const int g = lane >> 4;
  const f32x4 zero = {0.0f, 0.0f, 0.0f, 0.0f};
#pragma unroll
  for (int nt = 0; nt < 16; ++nt) gacc[nt] = zero;

#pragma unroll 1
  for (int c = 0; c < 8; ++c) {   // 8 chunks of 64 H-columns
    __syncthreads();              // prior stage consumers done
    stage32k(Upk + c * 16384, stage, tid);
    __syncthreads();              // U chunk landed

    f32x4 hacc[4];
#pragma unroll
    for (int t = 0; t < 4; ++t) hacc[t] = zero;
#pragma unroll
    for (int kt = 0; kt < 8; ++kt) {
#pragma unroll
      for (int t = 0; t < 4; ++t) {
        bf16x8 b = *reinterpret_cast<const bf16x8*>(
            &stage[((t * 8 + kt) * 64 + lane) * 8]);
        hacc[t] = __builtin_amdgcn_mfma_f32_16x16x32_bf16(xf[kt], b, hacc[t], 0, 0, 0);
      }
    }
    // tanh -> per-wave LDS round-trip (C-order layout, conflict-free writes)
#pragma unroll
    for (int t = 0; t < 4; ++t) {
#pragma unroll
      for (int r = 0; r < 4; ++r)
        hxw[(t * 4 + r) * 64 + lane] = bf16b(tanh_fast(hacc[t][r]));
    }

    __syncthreads();              // all waves done reading U chunk
    stage32k(Wpk + c * 16384, stage, tid);
    __syncthreads();              // W chunk landed

#pragma unroll
    for (int s = 0; s < 2; ++s) { // two K=32 steps within the 64-col chunk
      // A-frag of H: lane wants row=l&15, col = 32s + 8*(l>>4) + j  (j=0..7)
      // storage index I(row,col) = ((col>>4)*4 + (row&3))*64 + (row>>2)*16 + (col&15)
      int colhi = 2 * s + (g >> 1);
      int i0 = (colhi * 4 + (lane & 3)) * 64 + ((lane >> 2) & 3) * 16 + (g & 1) * 8;
      bf16x8 af = *reinterpret_cast<const bf16x8*>(&hxw[i0]);
#pragma unroll
      for (int nt = 0; nt < 16; ++nt) {
        bf16x8 b = *reinterpret_cast<const bf16x8*>(
            &stage[((s * 16 + nt) * 64 + lane) * 8]);
        gacc[nt] = __builtin_amdgcn_mfma_f32_16x16x32_bf16(af, b, gacc[nt], 0, 0, 0);
      }
    }
  }
}

__global__ __launch_bounds__(256, 2) void leapfrog_main(
    const float* __restrict__ xg, const float* __restrict__ vg,
    const float* __restrict__ fg,
    const unsigned short* __restrict__ Upk,
    const unsigned short* __restrict__ Wpk,
    float* __restrict__ outx, float* __restrict__ outv) {

  __shared__ unsigned short stage[16384];   // 32 KB: U-chunk or W-chunk
  __shared__ unsigned short hbuf[4][4096];  // 8 KB/wave: H round-trip + x_new staging

  const int tid  = threadIdx.x;
  const int w    = tid >> 6;
  const int lane = tid & 63;
  const int g    = lane >> 4;
  const int cl   = lane & 15;
  const int rowbase = blockIdx.x * 64 + w * 16;
  unsigned short* hxw = hbuf[w];

  // ---- pass-1 A fragments from x (16 rows of this wave) ----
  bf16x8 xf[8];
  {
    const float* xrow = xg + (size_t)(rowbase + cl) * DDIM;
#pragma unroll
    for (int kt = 0; kt < 8; ++kt) {
      const float* p = xrow + kt * 32 + g * 8;
      bf16x8 f;
#pragma unroll
      for (int j = 0; j < 8; ++j) f[j] = (__bf16)p[j];
      xf[kt] = f;
    }
  }

  f32x4 gacc[16];
  gemm_chain(xf, gacc, Upk, Wpk, stage, hxw, tid, lane);   // gamma / v

  // ---- pass-1 epilogue: half-kick + drift; stash x_new (bf16) + v_half ----
  unsigned int vhp[32];
#pragma unroll
  for (int nt = 0; nt < 16; ++nt) {
    float vh4[4];
#pragma unroll
    for (int r = 0; r < 4; ++r) {
      int lrow = 4 * g + r;
      size_t idx = (size_t)(rowbase + lrow) * DDIM + nt * 16 + cl;
      float vv = vg[idx], ff = fg[idx], xx = xg[idx];
      float gam = gacc[nt][r] * vv;
      float vh  = vv + HDT_C * (ff - gam);
      float xn  = xx + DT_C * vh;
      outx[idx] = xn;
      hxw[lrow * 256 + nt * 16 + cl] = bf16b(xn);  // A-layout staging for pass 2
      vh4[r] = vh;
    }
    vhp[nt * 2 + 0] = (unsigned)bf16b(vh4[0]) | ((unsigned)bf16b(vh4[1]) << 16);
    vhp[nt * 2 + 1] = (unsigned)bf16b(vh4[2]) | ((unsigned)bf16b(vh4[3]) << 16);
  }
  // pass-2 A fragments from staged x_new (then hxw is free for H round-trip)
#pragma unroll
  for (int kt = 0; kt < 8; ++kt)
    xf[kt] = *reinterpret_cast<const bf16x8*>(&hxw[cl * 256 + kt * 32 + g * 8]);

  gemm_chain(xf, gacc, Upk, Wpk, stage, hxw, tid, lane);   // gamma_half / v_half

  // ---- final epilogue: second half-kick ----
#pragma unroll
  for (int nt = 0; nt < 16; ++nt) {
#pragma unroll
    for (int r = 0; r < 4; ++r) {
      size_t idx = (size_t)(rowbase + 4 * g + r) * DDIM + nt * 16 + cl;
      float ff = fg[idx];
      unsigned pv = vhp[nt * 2 + (r >> 1)];
      float vh = bf16f((unsigned short)((r & 1) ? (pv >> 16) : (pv & 0xffffu)));
      float gam = gacc[nt][r] * vh;
      outv[idx] = vh + HDT_C * (ff - gam);
    }
  }
}

extern "C" void kernel_launch(void* const* d_in, const int* in_sizes, int n_in,
                              void* d_out, int out_size, void* d_ws, size_t ws_size,
                              hipStream_t stream) {
  const float* x = (const float*)d_in[0];
  const float* v = (const float*)d_in[1];
  const float* f = (const float*)d_in[2];
  const float* U = (const float*)d_in[3];   // [256][512]
  const float* W = (const float*)d_in[4];   // [512][256]

  unsigned short* Upk = (unsigned short*)d_ws;          // 256 KB
  unsigned short* Wpk = Upk + 131072;                   // 256 KB
  float* outx = (float*)d_out;
  float* outv = outx + (size_t)BATCH * DDIM;

  hipLaunchKernelGGL(pack_uw, dim3(128), dim3(256), 0, stream, U, W, Upk, Wpk);
  hipLaunchKernelGGL(leapfrog_main, dim3(BATCH / 64), dim3(256), 0, stream,
                     x, v, f, Upk, Wpk, outx, outv);
}

// Round 8
// 360.799 us; speedup vs baseline: 1.0124x; 1.0124x over previous
//
#include <hip/hip_runtime.h>
#include <hip/hip_bf16.h>

#define BATCH 65536
#define DDIM  256
#define HDIM  512
#define DT_C  0.1f
#define HDT_C 0.05f

typedef __attribute__((ext_vector_type(8))) __bf16 bf16x8;
typedef __attribute__((ext_vector_type(4))) float  f32x4;

__device__ __forceinline__ unsigned short bf16b(float f) {
  __bf16 h = (__bf16)f;
  return __builtin_bit_cast(unsigned short, h);
}
__device__ __forceinline__ float bf16f(unsigned short u) {
  unsigned int b = ((unsigned int)u) << 16;
  return __builtin_bit_cast(float, b);
}
__device__ __forceinline__ float tanh_fast(float x) {
  // tanh(x) = 1 - 2/(e^{2x}+1); stable at both tails
  float e = __expf(2.0f * x);
  return 1.0f - 2.0f * __builtin_amdgcn_rcpf(e + 1.0f);
}

// ---------------------------------------------------------------------------
// k-slot mapping: element j of lane l covers k = kt*32 + (l>>4)*8 + j, used
// consistently for A and B everywhere (permutation-invariant contraction).
// U_pk: [nt(32)][kt(8)][lane(64)][j(8)]  (n = nt*16 + (l&15), k over D=256)
// W_pk: [kt(16)][nt(16)][lane(64)][j(8)] (n = nt*16 + (l&15), k over H=512)
// 32 KB contiguous per 64-wide H-column chunk.
// ---------------------------------------------------------------------------
__global__ __launch_bounds__(256) void pack_uw(
    const float* __restrict__ U, const float* __restrict__ W,
    unsigned short* __restrict__ Upk, unsigned short* __restrict__ Wpk) {
  int t = blockIdx.x * 256 + threadIdx.x;   // 32768 threads, 16B out each
  int lane = t & 63;
  int g = lane >> 4, cl = lane & 15;
  alignas(16) unsigned short o[8];
  if (t < 16384) {
    int ktnt = t >> 6;
    int kt = ktnt & 7, nt = ktnt >> 3;
    int k0 = kt * 32 + g * 8, n = nt * 16 + cl;
#pragma unroll
    for (int j = 0; j < 8; ++j) o[j] = bf16b(U[(size_t)(k0 + j) * HDIM + n]);
    *reinterpret_cast<uint4*>(Upk + (size_t)t * 8) =
        *reinterpret_cast<const uint4*>(o);
  } else {
    int s = t - 16384;
    int ktnt = s >> 6;
    int nt = ktnt & 15, kt = ktnt >> 4;
    int k0 = kt * 32 + g * 8, n = nt * 16 + cl;
#pragma unroll
    for (int j = 0; j < 8; ++j) o[j] = bf16b(W[(size_t)(k0 + j) * DDIM + n]);
    *reinterpret_cast<uint4*>(Wpk + (size_t)s * 8) =
        *reinterpret_cast<const uint4*>(o);
  }
}

// ---------------------------------------------------------------------------
// Pipelined main kernel: 512 threads (8 waves), 128 rows/block, 512 blocks.
// LDS (dynamic, 144 KB): 4-slot stage ring (4 x 32 KB) + 8 x 2 KB hbuf.
// 32 phases/chain-pair (even = U-chunk, odd = W-chunk), stage prefetch is
// 2 phases deep with counted s_waitcnt vmcnt(4) at phase tops (never 0 in
// the steady-state loop).
// ---------------------------------------------------------------------------
__global__ __launch_bounds__(512, 2) void leapfrog_main(
    const float* __restrict__ xg, const float* __restrict__ vg,
    const float* __restrict__ fg,
    const unsigned short* __restrict__ Upk,
    const unsigned short* __restrict__ Wpk,
    float* __restrict__ outx, float* __restrict__ outv) {

  extern __shared__ unsigned short smem[];  // [4*16384 stage][8*1024 hbuf]

  const int tid  = threadIdx.x;
  const int w    = tid >> 6;
  const int lane = tid & 63;
  const int g    = lane >> 4;
  const int cl   = lane & 15;
  const int rowbase = blockIdx.x * 128 + w * 16;
  unsigned short* hxw = smem + 65536 + w * 1024;

  // stage one 32 KB chunk: 512 threads x 4 x 16 B (wave-uniform LDS base)
  auto STAGE = [&](int slot, const unsigned short* src) {
    const char* s = reinterpret_cast<const char*>(src);
    char* d = reinterpret_cast<char*>(smem) + slot * 32768;
#pragma unroll
    for (int i = 0; i < 4; ++i) {
      int o = (i * 8 + w) * 1024;
      __builtin_amdgcn_global_load_lds(
          (const __attribute__((address_space(1))) void*)(s + o + lane * 16),
          (__attribute__((address_space(3))) void*)(d + o), 16, 0, 0);
    }
  };
  auto SRC = [&](int P) -> const unsigned short* {
    int q = P & 15, c = q >> 1;
    return ((q & 1) ? Wpk : Upk) + c * 16384;
  };
  auto PHASE_TOP = [&](int P) {
    if (P == 31) asm volatile("s_waitcnt vmcnt(0)" ::: "memory");
    else         asm volatile("s_waitcnt vmcnt(4)" ::: "memory");
    __builtin_amdgcn_s_barrier();
    asm volatile("" ::: "memory");   // keep LDS reads below the barrier
    if (P + 2 < 32) STAGE((P + 2) & 3, SRC(P + 2));
  };

  // ---- pass-1 A fragments from x (16 rows of this wave) ----
  bf16x8 xf[8];
  {
    const float* xrow = xg + (size_t)(rowbase + cl) * DDIM;
#pragma unroll
    for (int kt = 0; kt < 8; ++kt) {
      const float4* p4 = reinterpret_cast<const float4*>(xrow + kt * 32 + g * 8);
      float4 a = p4[0], b = p4[1];
      bf16x8 f;
      f[0] = (__bf16)a.x; f[1] = (__bf16)a.y; f[2] = (__bf16)a.z; f[3] = (__bf16)a.w;
      f[4] = (__bf16)b.x; f[5] = (__bf16)b.y; f[6] = (__bf16)b.z; f[7] = (__bf16)b.w;
      xf[kt] = f;
    }
  }

  const f32x4 zero = {0.0f, 0.0f, 0.0f, 0.0f};
  f32x4 gacc[16];
#pragma unroll
  for (int nt = 0; nt < 16; ++nt) gacc[nt] = zero;
  unsigned int vhp[32];

  // prologue: fill the first two ring slots
  STAGE(0, SRC(0));
  STAGE(1, SRC(1));

#pragma unroll 1
  for (int chain = 0; chain < 2; ++chain) {
#pragma unroll 1
    for (int c = 0; c < 8; ++c) {
      const int P = chain * 16 + c * 2;

      // ================= U phase (H-chunk c: hacc = x @ U_chunk) ==========
      PHASE_TOP(P);

      if (chain == 1 && c == 0) {
        // ---- chain boundary: half-kick + drift (overlaps stage 17/18) ----
#pragma unroll
        for (int ntg = 0; ntg < 4; ++ntg) {
#pragma unroll
          for (int nt4 = 0; nt4 < 4; ++nt4) {
            int nt = ntg * 4 + nt4;
            float vh4[4];
#pragma unroll
            for (int r = 0; r < 4; ++r) {
              int lrow = 4 * g + r;
              size_t idx = (size_t)(rowbase + lrow) * DDIM + nt * 16 + cl;
              float vv = vg[idx], ff = fg[idx], xx = xg[idx];
              float gam = gacc[nt][r] * vv;
              float vh  = vv + HDT_C * (ff - gam);
              float xn  = xx + DT_C * vh;
              outx[idx] = xn;
              hxw[lrow * 64 + nt4 * 16 + cl] = bf16b(xn);
              vh4[r] = vh;
            }
            vhp[nt * 2 + 0] = (unsigned)bf16b(vh4[0]) | ((unsigned)bf16b(vh4[1]) << 16);
            vhp[nt * 2 + 1] = (unsigned)bf16b(vh4[2]) | ((unsigned)bf16b(vh4[3]) << 16);
          }
          // per-wave LDS transpose: C-layout x_new -> A-frags (cols ntg*64..+63)
#pragma unroll
          for (int q = 0; q < 2; ++q)
            xf[ntg * 2 + q] =
                *reinterpret_cast<const bf16x8*>(&hxw[cl * 64 + q * 32 + g * 8]);
        }
#pragma unroll
        for (int nt = 0; nt < 16; ++nt) gacc[nt] = zero;
      }

      {
        const unsigned short* sb = smem + (P & 3) * 16384;
        f32x4 hacc[4];
#pragma unroll
        for (int t = 0; t < 4; ++t) hacc[t] = zero;
        __builtin_amdgcn_s_setprio(1);
#pragma unroll
        for (int kt = 0; kt < 8; ++kt) {
#pragma unroll
          for (int t = 0; t < 4; ++t) {
            bf16x8 b = *reinterpret_cast<const bf16x8*>(
                &sb[((t * 8 + kt) * 64 + lane) * 8]);
            hacc[t] = __builtin_amdgcn_mfma_f32_16x16x32_bf16(xf[kt], b, hacc[t], 0, 0, 0);
          }
        }
        __builtin_amdgcn_s_setprio(0);
        // tanh -> per-wave hbuf (C-order, read back next phase)
#pragma unroll
        for (int t = 0; t < 4; ++t)
#pragma unroll
          for (int r = 0; r < 4; ++r)
            hxw[(t * 4 + r) * 64 + lane] = bf16b(tanh_fast(hacc[t][r]));
      }

      // ================= W phase (gacc += tanh(..) @ W_chunk) =============
      PHASE_TOP(P + 1);
      {
        const unsigned short* sb = smem + ((P + 1) & 3) * 16384;
        __builtin_amdgcn_s_setprio(1);
#pragma unroll
        for (int s = 0; s < 2; ++s) {
          // A-frag of H: lane row=l&15, col = 32s + 8*(l>>4) + j
          int colhi = 2 * s + (g >> 1);
          int i0 = (colhi * 4 + (lane & 3)) * 64 + ((lane >> 2) & 3) * 16 + (g & 1) * 8;
          bf16x8 af = *reinterpret_cast<const bf16x8*>(&hxw[i0]);
#pragma unroll
          for (int nt = 0; nt < 16; ++nt) {
            bf16x8 b = *reinterpret_cast<const bf16x8*>(
                &sb[((s * 16 + nt) * 64 + lane) * 8]);
            gacc[nt] = __builtin_amdgcn_mfma_f32_16x16x32_bf16(af, b, gacc[nt], 0, 0, 0);
          }
        }
        __builtin_amdgcn_s_setprio(0);
      }
    }
  }

  // ---- final epilogue: second half-kick ----
#pragma unroll
  for (int nt = 0; nt < 16; ++nt) {
#pragma unroll
    for (int r = 0; r < 4; ++r) {
      size_t idx = (size_t)(rowbase + 4 * g + r) * DDIM + nt * 16 + cl;
      float ff = fg[idx];
      unsigned pv = vhp[nt * 2 + (r >> 1)];
      float vh = bf16f((unsigned short)((r & 1) ? (pv >> 16) : (pv & 0xffffu)));
      float gam = gacc[nt][r] * vh;
      outv[idx] = vh + HDT_C * (ff - gam);
    }
  }
}

extern "C" void kernel_launch(void* const* d_in, const int* in_sizes, int n_in,
                              void* d_out, int out_size, void* d_ws, size_t ws_size,
                              hipStream_t stream) {
  const float* x = (const float*)d_in[0];
  const float* v = (const float*)d_in[1];
  const float* f = (const float*)d_in[2];
  const float* U = (const float*)d_in[3];   // [256][512]
  const float* W = (const float*)d_in[4];   // [512][256]

  unsigned short* Upk = (unsigned short*)d_ws;          // 256 KB
  unsigned short* Wpk = Upk + 131072;                   // 256 KB
  float* outx = (float*)d_out;
  float* outv = outx + (size_t)BATCH * DDIM;

  // 144 KB dynamic LDS (> 64 KB static limit); idempotent, every call.
  hipFuncSetAttribute(reinterpret_cast<const void*>(leapfrog_main),
                      hipFuncAttributeMaxDynamicSharedMemorySize, 147456);

  hipLaunchKernelGGL(pack_uw, dim3(128), dim3(256), 0, stream, U, W, Upk, Wpk);
  hipLaunchKernelGGL(leapfrog_main, dim3(BATCH / 128), dim3(512), 147456, stream,
                     x, v, f, Upk, Wpk, outx, outv);
}